// Round 1
// baseline (193.423 us; speedup 1.0000x reference)
//
#include <hip/hip_runtime.h>
#include <hip/hip_bf16.h>
#include <stdint.h>

// Shapes (fixed for this problem)
#define B_   4
#define H_   16
#define S_   1024
#define D_   128
#define BM   128                 // Q rows per block
#define BN   64                  // K/V rows per iteration
#define NKT  (S_ / BN)           // 16
#define NTHREADS 256             // 4 waves

typedef float f32x4 __attribute__((ext_vector_type(4)));
typedef short s16x8 __attribute__((ext_vector_type(8)));   // 8 bf16 (MFMA A/B frag)
typedef short s16x4 __attribute__((ext_vector_type(4)));
typedef int   i32x4 __attribute__((ext_vector_type(4)));

static __device__ __forceinline__ uint16_t f2bf(float f) {
  uint32_t u = __float_as_uint(f);
  u += 0x7FFFu + ((u >> 16) & 1u);          // round-to-nearest-even
  return (uint16_t)(u >> 16);
}
static __device__ __forceinline__ float bf2f(uint16_t h) {
  return __uint_as_float((uint32_t)h << 16);
}

// XOR swizzle (G4): spreads row-major 256B/128B-stride LDS rows across 16B slots.
// All writers and readers of a given tile use the same formula -> consistent.

__global__ __launch_bounds__(NTHREADS, 2)
void attn_relu15_kernel(const float* __restrict__ q, const float* __restrict__ k,
                        const float* __restrict__ v, const int* __restrict__ mask,
                        float* __restrict__ outp, float* __restrict__ attnp)
{
  // XCD-grouped mapping (bijective, 512 = 8 XCD * 64): the 8 q-tiles of a head
  // land on the same XCD so its K/V (1 MB) stays in that XCD's L2.
  const int blk = blockIdx.x;
  const int bh  = (blk & 7) * 8 + (blk >> 6);   // 0..63
  const int qt  = (blk >> 3) & 7;               // 0..7
  const int b   = bh >> 4;

  const int tid  = threadIdx.x;
  const int lane = tid & 63;
  const int wave = tid >> 6;
  const int wr = wave >> 1;       // 64-row half (S rows / O rows)
  const int wc = wave & 1;        // col half (S: 32-col, O: 64-col)

  __shared__ __align__(16) uint16_t lQ [BM * D_];   // [qrow][d]        32 KB
  __shared__ __align__(16) uint16_t lKS[BN * D_];   // K:[kr][d] -> S:[qr][kc] 16 KB
  __shared__ __align__(16) uint16_t lV [D_ * BN];   // Vt:[d][kc]       16 KB
  // total 64 KB -> 2 blocks/CU

  const float* qg = q + (size_t)bh * (S_ * D_) + (size_t)qt * BM * D_;
  const float* kg = k + (size_t)bh * (S_ * D_);
  const float* vg = v + (size_t)bh * (S_ * D_);
  const int*   mg = mask  + (size_t)b  * S_ * S_ + (size_t)qt * BM * S_;
  float*       ag = attnp + (size_t)bh * S_ * S_ + (size_t)qt * BM * S_;
  float*       og = outp  + (size_t)bh * (S_ * D_) + (size_t)qt * BM * D_;

  const float invT = 0.08838834764831843f;   // 1/sqrt(128)

  // ---- stage Q (scaled, f32 -> bf16), fully coalesced global reads ----
  #pragma unroll
  for (int rep = 0; rep < 16; ++rep) {
    int flat = (tid + NTHREADS * rep) * 4;          // 128*128 elems
    int r = flat >> 7, c = flat & 127;
    f32x4 x = *(const f32x4*)(qg + flat);
    s16x4 h;
    h[0] = (short)f2bf(x[0] * invT); h[1] = (short)f2bf(x[1] * invT);
    h[2] = (short)f2bf(x[2] * invT); h[3] = (short)f2bf(x[3] * invT);
    int byt = r * 256 + ((c * 2) ^ ((r & 7) << 4));
    *(s16x4*)((char*)lQ + byt) = h;
  }

  const f32x4 zero4 = {0.f, 0.f, 0.f, 0.f};
  f32x4 oacc[4][4];
  #pragma unroll
  for (int i = 0; i < 4; ++i)
    #pragma unroll
    for (int j = 0; j < 4; ++j)
      oacc[i][j] = zero4;

  for (int kt = 0; kt < NKT; ++kt) {
    __syncthreads();   // prev PV (and Q-stage on kt==0) drained before restaging

    // ---- stage K tile [BN][D] -> lKS (bf16) ----
    const float* kgt = kg + (size_t)kt * BN * D_;
    #pragma unroll
    for (int rep = 0; rep < 8; ++rep) {
      int flat = (tid + NTHREADS * rep) * 4;        // 64*128 elems
      int r = flat >> 7, c = flat & 127;
      f32x4 x = *(const f32x4*)(kgt + flat);
      s16x4 h;
      h[0] = (short)f2bf(x[0]); h[1] = (short)f2bf(x[1]);
      h[2] = (short)f2bf(x[2]); h[3] = (short)f2bf(x[3]);
      int byt = r * 256 + ((c * 2) ^ ((r & 7) << 4));
      *(s16x4*)((char*)lKS + byt) = h;
    }

    // ---- stage V tile transposed -> lV[d][kc], 4x4 quad-shuffle transpose ----
    const float* vgt = vg + (size_t)kt * BN * D_;
    #pragma unroll
    for (int rep = 0; rep < 8; ++rep) {
      int bid = (tid >> 2) + 64 * rep;              // 512 4x4 blocks: 16(k) x 32(d)
      int kb = bid >> 5, db = bid & 31;
      int l2 = lane & 3;
      f32x4 x = *(const f32x4*)(vgt + (size_t)(kb * 4 + l2) * D_ + db * 4);
      float v0 = x[0], v1 = x[1], v2 = x[2], v3 = x[3], t;
      t = (l2 & 1) ? v0 : v1; t = __shfl_xor(t, 1); if (l2 & 1) v0 = t; else v1 = t;
      t = (l2 & 1) ? v2 : v3; t = __shfl_xor(t, 1); if (l2 & 1) v2 = t; else v3 = t;
      t = (l2 & 2) ? v0 : v2; t = __shfl_xor(t, 2); if (l2 & 2) v0 = t; else v2 = t;
      t = (l2 & 2) ? v1 : v3; t = __shfl_xor(t, 2); if (l2 & 2) v1 = t; else v3 = t;
      // lane now holds column (d = 4*db + l2), rows k = 4*kb .. 4*kb+3
      int dd = db * 4 + l2;
      s16x4 h;
      h[0] = (short)f2bf(v0); h[1] = (short)f2bf(v1);
      h[2] = (short)f2bf(v2); h[3] = (short)f2bf(v3);
      int byt = dd * 128 + ((kb * 8) ^ ((dd & 7) << 4));
      *(s16x4*)((char*)lV + byt) = h;
    }
    __syncthreads();

    // ---- QK^T: S[128][64], per wave 64x32 ----
    f32x4 sacc[4][2];
    #pragma unroll
    for (int i = 0; i < 4; ++i) { sacc[i][0] = zero4; sacc[i][1] = zero4; }
    #pragma unroll
    for (int ks = 0; ks < 4; ++ks) {                // D=128 / K=32
      s16x8 af[4], bfr[2];
      #pragma unroll
      for (int mt = 0; mt < 4; ++mt) {
        int r = 64 * wr + 16 * mt + (lane & 15);
        int byt = r * 256 + (((ks * 64) + ((lane >> 4) * 16)) ^ ((r & 7) << 4));
        af[mt] = *(s16x8*)((char*)lQ + byt);
      }
      #pragma unroll
      for (int nt = 0; nt < 2; ++nt) {
        int r = 32 * wc + 16 * nt + (lane & 15);    // K row (= S col)
        int byt = r * 256 + (((ks * 64) + ((lane >> 4) * 16)) ^ ((r & 7) << 4));
        bfr[nt] = *(s16x8*)((char*)lKS + byt);
      }
      #pragma unroll
      for (int mt = 0; mt < 4; ++mt)
        #pragma unroll
        for (int nt = 0; nt < 2; ++nt)
          sacc[mt][nt] = __builtin_amdgcn_mfma_f32_16x16x32_bf16(
              af[mt], bfr[nt], sacc[mt][nt], 0, 0, 0);
    }
    __syncthreads();   // all waves done reading lKS as K

    // ---- clip + bf16, write S into lKS as [qrow][kcol] ----
    #pragma unroll
    for (int mt = 0; mt < 4; ++mt) {
      #pragma unroll
      for (int nt = 0; nt < 2; ++nt) {
        int c = 32 * wc + 16 * nt + (lane & 15);
        #pragma unroll
        for (int j = 0; j < 4; ++j) {
          int r = 64 * wr + 16 * mt + 4 * (lane >> 4) + j;
          float val = fminf(fmaxf(sacc[mt][nt][j], 0.f), 15.f);
          int byt = r * 128 + ((c * 2) ^ ((r & 7) << 4));
          *(uint16_t*)((char*)lKS + byt) = f2bf(val);
        }
      }
    }
    __syncthreads();

    // ---- linear pass: mask + coalesced attn write + masked S write-back ----
    #pragma unroll
    for (int rep = 0; rep < 4; ++rep) {
      int flat = (tid + NTHREADS * rep) * 8;        // 128*64 elems
      int r = flat >> 6, c = flat & 63;
      int byt = r * 128 + ((c * 2) ^ ((r & 7) << 4));
      s16x8 sv = *(s16x8*)((char*)lKS + byt);
      const int* mrow = mg + (size_t)r * S_ + kt * BN + c;
      i32x4 m0 = *(const i32x4*)(mrow);
      i32x4 m1 = *(const i32x4*)(mrow + 4);
      f32x4 a0, a1;
      #pragma unroll
      for (int i = 0; i < 4; ++i) {
        if (m0[i] == 0) sv[i] = 0;
        a0[i] = bf2f((uint16_t)sv[i]);
        if (m1[i] == 0) sv[4 + i] = 0;
        a1[i] = bf2f((uint16_t)sv[4 + i]);
      }
      float* arow = ag + (size_t)r * S_ + kt * BN + c;
      __builtin_nontemporal_store(a0, (f32x4*)(arow));      // attn is a pure stream
      __builtin_nontemporal_store(a1, (f32x4*)(arow + 4));
      *(s16x8*)((char*)lKS + byt) = sv;                     // masked S for PV
    }
    __syncthreads();

    // ---- PV: O += S @ V, per wave 64x64 ----
    #pragma unroll
    for (int ks = 0; ks < 2; ++ks) {                // BN=64 / K=32
      s16x8 saf[4], vbf[4];
      #pragma unroll
      for (int mt = 0; mt < 4; ++mt) {
        int r = 64 * wr + 16 * mt + (lane & 15);
        int byt = r * 128 + (((ks * 64) + ((lane >> 4) * 16)) ^ ((r & 7) << 4));
        saf[mt] = *(s16x8*)((char*)lKS + byt);
      }
      #pragma unroll
      for (int nt = 0; nt < 4; ++nt) {
        int dd = 64 * wc + 16 * nt + (lane & 15);   // output d (= Vt row)
        int byt = dd * 128 + (((ks * 64) + ((lane >> 4) * 16)) ^ ((dd & 7) << 4));
        vbf[nt] = *(s16x8*)((char*)lV + byt);
      }
      #pragma unroll
      for (int mt = 0; mt < 4; ++mt)
        #pragma unroll
        for (int nt = 0; nt < 4; ++nt)
          oacc[mt][nt] = __builtin_amdgcn_mfma_f32_16x16x32_bf16(
              saf[mt], vbf[nt], oacc[mt][nt], 0, 0, 0);
    }
  }

  // ---- epilogue: write O (f32) ----
  #pragma unroll
  for (int mt = 0; mt < 4; ++mt) {
    #pragma unroll
    for (int nt = 0; nt < 4; ++nt) {
      int n = 64 * wc + 16 * nt + (lane & 15);
      #pragma unroll
      for (int j = 0; j < 4; ++j) {
        int m = 64 * wr + 16 * mt + 4 * (lane >> 4) + j;
        og[(size_t)m * D_ + n] = oacc[mt][nt][j];
      }
    }
  }
}

extern "C" void kernel_launch(void* const* d_in, const int* in_sizes, int n_in,
                              void* d_out, int out_size, void* d_ws, size_t ws_size,
                              hipStream_t stream) {
  const float* q    = (const float*)d_in[0];
  const float* k    = (const float*)d_in[1];
  const float* v    = (const float*)d_in[2];
  const int*   mask = (const int*)d_in[3];
  float* outp  = (float*)d_out;
  float* attnp = outp + (size_t)B_ * H_ * S_ * D_;   // tuple: (out, attn) concatenated
  dim3 grid(B_ * H_ * (S_ / BM));                    // 512 blocks
  attn_relu15_kernel<<<grid, NTHREADS, 0, stream>>>(q, k, v, mask, outp, attnp);
}